// Round 1
// baseline (486.764 us; speedup 1.0000x reference)
//
#include <hip/hip_runtime.h>
#include <math.h>

// ---------------- problem constants ----------------
constexpr int NFFT  = 256;
constexpr int HOP   = 64;
constexpr int NBIN  = 129;          // rfft bins
constexpr int NB    = 8;            // batch
constexpr int LMIX  = 65536;
constexpr int LAUX  = 262144;
constexpr int TM    = 1025;         // mix frames
constexpr int TA    = 4097;         // aux frames
constexpr int TROWS = 4175;         // aux frames + zero pad (78)
constexpr int HS    = 126;
constexpr int W     = 26;           // windows
constexpr int NJOBS = NB * W;       // 208
constexpr int NVAL  = TM * NBIN;    // 132225 values per (b,w)
constexpr int KMED  = (NVAL - 1) / 2; // 66112
constexpr int CHUNKS = 8;           // blocks per job in sim passes

// ---------------- workspace layout (bytes) ----------------
constexpr size_t MIXS_OFF  = 0;
constexpr size_t MIXS_BYTES = (size_t)NB * TM * NBIN * sizeof(float2);      // 8,462,400
constexpr size_t AUXS_OFF  = MIXS_OFF + MIXS_BYTES;
constexpr size_t AUXS_BYTES = (size_t)NB * TROWS * NBIN * sizeof(float2);   // 34,468,800
constexpr size_t HIST_OFF  = AUXS_OFF + AUXS_BYTES;
constexpr size_t HIST_BYTES = (size_t)NJOBS * CHUNKS * 2048 * 4;            // 13,631,488
constexpr size_t NAN_OFF   = HIST_OFF + HIST_BYTES;
constexpr size_t NAN_BYTES = (size_t)NJOBS * 4;
constexpr size_t PREF_OFF  = NAN_OFF + 832;
constexpr size_t KREM_OFF  = PREF_OFF + 832;
constexpr size_t MED_OFF   = KREM_OFF + 832;
constexpr size_t BEST_OFF  = MED_OFF + 832;
constexpr size_t WS_TOTAL  = BEST_OFF + 64;
constexpr size_t MEMSET_BYTES = HIST_BYTES + NAN_BYTES;                      // hist + nan counters

// ---------------- STFT: naive 256-tap DFT per bin ----------------
// out[(b*Trows + fr)*NBIN + k] = sum_n x[reflect(fr*HOP + n - 128)] * e^{-2pi i k n /256}
template<int FPB>
__global__ void stft_kernel(const float* __restrict__ x, int L, int Tframes, int Trows,
                            float2* __restrict__ out)
{
    __shared__ float  xs[FPB][NFFT];
    __shared__ float2 tw[NFFT];
    const int tid = threadIdx.x;
    const int b   = blockIdx.y;
    const int f0  = blockIdx.x * FPB;

    // twiddle table, double-precision accurate: tw[j] = (cos(2pi j/256), -sin(2pi j/256))
    {
        double ang = (double)tid * (-2.0 * 3.14159265358979323846 / 256.0);
        tw[tid] = make_float2((float)cos(ang), (float)sin(ang));
    }
    // load frames (reflect padding)
    for (int f = 0; f < FPB; ++f) {
        int fr = f0 + f;
        if (fr < Tframes) {
            int j = fr * HOP + tid - 128;
            if (j < 0) j = -j;
            if (j >= L) j = 2 * L - 2 - j;
            xs[f][tid] = x[(size_t)b * L + j];
        }
    }
    __syncthreads();

    const int nj = FPB * NBIN;
    for (int jj = tid; jj < nj; jj += blockDim.x) {
        int f  = jj / NBIN;
        int k  = jj - f * NBIN;
        int fr = f0 + f;
        if (fr >= Trows) continue;
        float re = 0.f, im = 0.f;
        if (fr < Tframes) {
            int idx = 0;
            #pragma unroll 8
            for (int n = 0; n < NFFT; ++n) {
                float2 t = tw[idx];
                float  v = xs[f][n];
                re = fmaf(v, t.x, re);
                im = fmaf(v, t.y, im);
                idx = (idx + k) & 255;
            }
        }
        out[((size_t)b * Trows + fr) * NBIN + k] = make_float2(re, im);
    }
}

// ---------------- sortable key flip ----------------
__device__ __forceinline__ unsigned flip_key(float s) {
    unsigned u = __float_as_uint(s);
    return (u & 0x80000000u) ? ~u : (u | 0x80000000u);
}

// ---------------- similarity + histogram passes ----------------
// PASS 1: bin = key>>21 (11 bits), count NaNs
// PASS 2: among keys with top-11 == pref top-11, bin = (key>>10)&2047
// PASS 3: among keys with top-22 == pref top-22, bin = key & 1023
template<int PASS>
__global__ void sim_pass(const float2* __restrict__ mixS, const float2* __restrict__ auxS,
                         unsigned* __restrict__ hist, unsigned* __restrict__ nanCnt,
                         const unsigned* __restrict__ pref)
{
    __shared__ unsigned lh[2048];
    const int tid   = threadIdx.x;
    const int chunk = blockIdx.x;   // 0..CHUNKS-1
    const int job   = blockIdx.y;   // 0..207
    const int b = job / W;
    const int w = job - b * W;

    for (int i = tid; i < 2048; i += 256) lh[i] = 0;
    unsigned p = (PASS == 1) ? 0u : pref[job];
    __syncthreads();

    unsigned localnan = 0;
    const float2* mrow = mixS + (size_t)b * TM * NBIN;
    const float2* arow = auxS + ((size_t)b * TROWS + (size_t)w * HS) * NBIN;

    for (int i = chunk * 256 + tid; i < NVAL; i += CHUNKS * 256) {
        float2 m = mrow[i];
        float2 a = arow[i];
        float dot = m.x * a.x + m.y * a.y;
        float den = sqrtf(m.x * m.x + m.y * m.y) * sqrtf(a.x * a.x + a.y * a.y);
        float s = dot / den;
        unsigned key = flip_key(s);
        if (PASS == 1) {
            if (!(s == s)) localnan++;
            atomicAdd(&lh[key >> 21], 1u);
        } else if (PASS == 2) {
            if ((key >> 21) == (p >> 21)) atomicAdd(&lh[(key >> 10) & 2047u], 1u);
        } else {
            if ((key >> 10) == (p >> 10)) atomicAdd(&lh[key & 1023u], 1u);
        }
    }
    __syncthreads();

    unsigned* gh = hist + ((size_t)job * CHUNKS + chunk) * 2048;
    for (int i = tid; i < 2048; i += 256) gh[i] = lh[i];
    if (PASS == 1 && localnan) atomicAdd(&nanCnt[job], localnan);
}

// ---------------- per-pass scan: find bin containing target rank ----------------
template<int PASS>
__global__ void scan_pass(const unsigned* __restrict__ hist, unsigned* __restrict__ pref,
                          unsigned* __restrict__ krem, const unsigned* __restrict__ nanCnt,
                          float* __restrict__ med)
{
    constexpr int NBINS = (PASS == 3) ? 1024 : 2048;
    constexpr int PER   = NBINS / 256;
    __shared__ unsigned psum[256];
    __shared__ unsigned selseg;
    __shared__ unsigned selbase;
    const int tid = threadIdx.x;
    const int job = blockIdx.x;
    const unsigned* h = hist + (size_t)job * CHUNKS * 2048;

    unsigned bins[PER];
    unsigned s = 0;
    #pragma unroll
    for (int i = 0; i < PER; ++i) {
        unsigned v = 0;
        int bin = tid * PER + i;
        #pragma unroll
        for (int c = 0; c < CHUNKS; ++c) v += h[(size_t)c * 2048 + bin];
        bins[i] = v; s += v;
    }
    psum[tid] = s;
    __syncthreads();

    unsigned target = (PASS == 1) ? (unsigned)KMED : krem[job];
    if (tid == 0) {
        unsigned cum = 0; unsigned seg = 255, base = 0;
        for (int t2 = 0; t2 < 256; ++t2) {
            if (cum + psum[t2] > target) { seg = t2; base = cum; break; }
            cum += psum[t2];
        }
        selseg = seg; selbase = base;
    }
    __syncthreads();

    if (tid == (int)selseg) {
        unsigned cum = selbase;
        #pragma unroll
        for (int i = 0; i < PER; ++i) {
            if (cum + bins[i] > target) {
                unsigned bin = (unsigned)(tid * PER + i);
                if (PASS == 1) { pref[job] = bin << 21; krem[job] = target - cum; }
                else if (PASS == 2) { pref[job] |= bin << 10; krem[job] = target - cum; }
                else {
                    unsigned key = pref[job] | bin;
                    unsigned u = (key & 0x80000000u) ? (key ^ 0x80000000u) : ~key;
                    float v = __uint_as_float(u);
                    med[job] = (nanCnt[job] > 0u) ? -INFINITY : v;
                }
                break;
            }
            cum += bins[i];
        }
    }
}

// ---------------- argmax over windows (first-wins) ----------------
__global__ void argmax_kernel(const float* __restrict__ med, int* __restrict__ best)
{
    int b = threadIdx.x;
    if (b < NB) {
        float mx = -INFINITY; int bi = 0;
        for (int w = 0; w < W; ++w) {
            float v = med[b * W + w];
            if (v > mx) { mx = v; bi = w; }
        }
        best[b] = bi;
    }
}

// ---------------- emit selected window (real plane, imag plane) ----------------
__global__ void gather_kernel(const float2* __restrict__ auxS, const int* __restrict__ best,
                              float* __restrict__ out)
{
    int i = blockIdx.x * blockDim.x + threadIdx.x;
    if (i >= NB * NVAL) return;
    int b = i / NVAL;
    int r = i - b * NVAL;
    float2 v = auxS[((size_t)b * TROWS + (size_t)best[b] * HS) * NBIN + r];
    out[((size_t)(b * 2) + 0) * NVAL + r] = v.x;
    out[((size_t)(b * 2) + 1) * NVAL + r] = v.y;
}

// ---------------- launch ----------------
extern "C" void kernel_launch(void* const* d_in, const int* in_sizes, int n_in,
                              void* d_out, int out_size, void* d_ws, size_t ws_size,
                              hipStream_t stream)
{
    const float* mix = (const float*)d_in[0];
    const float* aux = (const float*)d_in[1];
    float* out = (float*)d_out;
    char* ws = (char*)d_ws;

    float2*   mixS = (float2*)(ws + MIXS_OFF);
    float2*   auxS = (float2*)(ws + AUXS_OFF);
    unsigned* hist = (unsigned*)(ws + HIST_OFF);
    unsigned* nanC = (unsigned*)(ws + NAN_OFF);
    unsigned* pref = (unsigned*)(ws + PREF_OFF);
    unsigned* krem = (unsigned*)(ws + KREM_OFF);
    float*    med  = (float*)(ws + MED_OFF);
    int*      best = (int*)(ws + BEST_OFF);

    // zero histograms + nan counters (state regions are written before read)
    hipMemsetAsync(hist, 0, MEMSET_BYTES, stream);

    constexpr int FPB = 4;
    stft_kernel<FPB><<<dim3((TM + FPB - 1) / FPB, NB), 256, 0, stream>>>(mix, LMIX, TM, TM, mixS);
    stft_kernel<FPB><<<dim3((TROWS + FPB - 1) / FPB, NB), 256, 0, stream>>>(aux, LAUX, TA, TROWS, auxS);

    sim_pass<1><<<dim3(CHUNKS, NJOBS), 256, 0, stream>>>(mixS, auxS, hist, nanC, pref);
    scan_pass<1><<<NJOBS, 256, 0, stream>>>(hist, pref, krem, nanC, med);
    sim_pass<2><<<dim3(CHUNKS, NJOBS), 256, 0, stream>>>(mixS, auxS, hist, nanC, pref);
    scan_pass<2><<<NJOBS, 256, 0, stream>>>(hist, pref, krem, nanC, med);
    sim_pass<3><<<dim3(CHUNKS, NJOBS), 256, 0, stream>>>(mixS, auxS, hist, nanC, pref);
    scan_pass<3><<<NJOBS, 256, 0, stream>>>(hist, pref, krem, nanC, med);

    argmax_kernel<<<1, 64, 0, stream>>>(med, best);
    gather_kernel<<<(NB * NVAL + 255) / 256, 256, 0, stream>>>(auxS, best, out);
}

// Round 2
// 303.620 us; speedup vs baseline: 1.6032x; 1.6032x over previous
//
#include <hip/hip_runtime.h>
#include <math.h>

// ---------------- problem constants ----------------
constexpr int NFFT  = 256;
constexpr int HOP   = 64;
constexpr int NBIN  = 129;          // rfft bins
constexpr int NB    = 8;            // batch
constexpr int LMIX  = 65536;
constexpr int LAUX  = 262144;
constexpr int TM    = 1025;         // mix frames
constexpr int TA    = 4097;         // aux frames
constexpr int TROWS = 4175;         // aux frames + zero pad (78)
constexpr int HS    = 126;
constexpr int W     = 26;           // windows
constexpr int NJOBS = NB * W;       // 208
constexpr int NVAL  = TM * NBIN;    // 132225 values per (b,w)
constexpr int KMED  = (NVAL - 1) / 2; // 66112
constexpr int CHUNKS = 8;           // blocks per job in sim passes

// ---------------- workspace layout (bytes) ----------------
constexpr size_t MIXS_OFF  = 0;
constexpr size_t MIXS_BYTES = (size_t)NB * TM * NBIN * sizeof(float2);      // 8,462,400
constexpr size_t AUXS_OFF  = MIXS_OFF + MIXS_BYTES;
constexpr size_t AUXS_BYTES = (size_t)NB * TROWS * NBIN * sizeof(float2);   // 34,468,800
constexpr size_t HIST_OFF  = AUXS_OFF + AUXS_BYTES;
constexpr size_t HIST_BYTES = (size_t)NJOBS * CHUNKS * 2048 * 4;            // 13,631,488
constexpr size_t TW_OFF    = HIST_OFF + HIST_BYTES;
constexpr size_t TW_BYTES  = 256 * sizeof(float2);
constexpr size_t NAN_OFF   = TW_OFF + TW_BYTES;
constexpr size_t NAN_BYTES = (size_t)NJOBS * 4;                              // 832
constexpr size_t PREF_OFF  = NAN_OFF + 832;
constexpr size_t KREM_OFF  = PREF_OFF + 832;
constexpr size_t MED_OFF   = KREM_OFF + 832;
constexpr size_t BEST_OFF  = MED_OFF + 832;

// ---------------- twiddle table: tw[i] = e^{-2*pi*i*j/256}, built in double ----------------
__global__ void build_table(float2* __restrict__ tw)
{
    int i = threadIdx.x;
    double ang = (double)i * (-2.0 * 3.14159265358979323846 / 256.0);
    tw[i] = make_float2((float)cos(ang), (float)sin(ang));
}

// ---------------- STFT via Cooley-Tukey 256 = 16 x 16 ----------------
// X[k] = sum_{n1=0..15} dk^{n1} * Y[n1][k mod 16],  dk = e^{-2pi i k/256}
// Y[n1][r] = sum_{n2=0..15} x[n1 + 16 n2] * e^{-2pi i r n2 / 16}
template<int FPB>
__global__ void stft_fft(const float* __restrict__ x, const float2* __restrict__ twg,
                         int L, int Tframes, int Trows, float2* __restrict__ out)
{
    constexpr int NX = 64 * (FPB - 1) + NFFT;   // shared sample span (448 for FPB=4)
    __shared__ float  xs[NX];
    __shared__ float2 Y[FPB][16][16];
    __shared__ float2 cis16[16];

    const int tid = threadIdx.x;
    const int b   = blockIdx.y;
    const int f0  = blockIdx.x * FPB;

    if (tid < 16) cis16[tid] = twg[(16 * tid) & 255];

    // load the union of this block's frames once (reflect padding)
    for (int i = tid; i < NX; i += 256) {
        int j = f0 * HOP + i - 128;
        if (j < 0) j = -j;
        if (j >= L) j = 2 * L - 2 - j;
        xs[i] = x[(size_t)b * L + j];
    }
    __syncthreads();

    // stage B: inner 16-point DFTs. thread owns fixed (n1, r), loops frames.
    const int n1 = (tid >> 4) & 15;
    const int r  = tid & 15;
    #pragma unroll
    for (int f = 0; f < FPB; ++f) {
        float re = 0.f, im = 0.f;
        int idx = 0;
        #pragma unroll
        for (int n2 = 0; n2 < 16; ++n2) {
            float  v = xs[f * HOP + n1 + 16 * n2];
            float2 t = cis16[idx];
            re = fmaf(v, t.x, re);
            im = fmaf(v, t.y, im);
            idx = (idx + r) & 15;
        }
        Y[f][n1][r] = make_float2(re, im);
    }
    __syncthreads();

    // stage C: combine with per-thread twiddle recurrence (no hot-loop table reads)
    for (int jj = tid; jj < FPB * NBIN; jj += 256) {
        int f  = jj / NBIN;
        int k  = jj - f * NBIN;
        int fr = f0 + f;
        if (fr >= Trows) continue;
        float2 o = make_float2(0.f, 0.f);
        if (fr < Tframes) {
            float2 dk = twg[k];
            float tr = 1.f, ti = 0.f;
            float ar = 0.f, ai = 0.f;
            #pragma unroll
            for (int s = 0; s < 16; ++s) {
                float2 y = Y[f][s][k & 15];
                ar = fmaf(tr, y.x, ar); ar = fmaf(-ti, y.y, ar);
                ai = fmaf(tr, y.y, ai); ai = fmaf( ti, y.x, ai);
                float nr = tr * dk.x - ti * dk.y;
                ti = fmaf(tr, dk.y, ti * dk.x);
                tr = nr;
            }
            o = make_float2(ar, ai);
        }
        out[((size_t)b * Trows + fr) * NBIN + k] = o;
    }
}

// ---------------- sortable key flip ----------------
__device__ __forceinline__ unsigned flip_key(float s) {
    unsigned u = __float_as_uint(s);
    return (u & 0x80000000u) ? ~u : (u | 0x80000000u);
}

// ---------------- similarity + histogram passes ----------------
// PASS 1: bin = key>>21 (11 bits), count NaNs
// PASS 2: among keys with top-11 == pref, bin = (key>>10)&2047
// PASS 3: among keys with top-22 == pref, bin = key & 1023
template<int PASS>
__global__ void sim_pass(const float2* __restrict__ mixS, const float2* __restrict__ auxS,
                         unsigned* __restrict__ hist, unsigned* __restrict__ nanCnt,
                         const unsigned* __restrict__ pref)
{
    constexpr int NCOPY   = 4;
    constexpr int HSTRIDE = 2049;                 // bank-offset copies
    __shared__ unsigned lh[NCOPY * HSTRIDE];      // 32,784 B
    const int tid   = threadIdx.x;
    const int chunk = blockIdx.x;   // 0..CHUNKS-1
    const int job   = blockIdx.y;   // 0..207
    const int b = job / W;
    const int w = job - b * W;
    const int copy = (tid >> 4) & (NCOPY - 1);    // 16 lanes per copy within a wave

    for (int i = tid; i < NCOPY * HSTRIDE; i += 256) lh[i] = 0;
    unsigned p = (PASS == 1) ? 0u : pref[job];
    __syncthreads();

    unsigned localnan = 0;
    const float2* mrow = mixS + (size_t)b * TM * NBIN;
    const float2* arow = auxS + ((size_t)b * TROWS + (size_t)w * HS) * NBIN;

    for (int i = chunk * 256 + tid; i < NVAL; i += CHUNKS * 256) {
        float2 m = mrow[i];
        float2 a = arow[i];
        float dot = m.x * a.x + m.y * a.y;
        float den = sqrtf((m.x * m.x + m.y * m.y) * (a.x * a.x + a.y * a.y));
        float s = dot / den;
        unsigned key = flip_key(s);
        if (PASS == 1) {
            if (!(s == s)) localnan++;
            atomicAdd(&lh[copy * HSTRIDE + (key >> 21)], 1u);
        } else if (PASS == 2) {
            if ((key >> 21) == (p >> 21)) atomicAdd(&lh[copy * HSTRIDE + ((key >> 10) & 2047u)], 1u);
        } else {
            if ((key >> 10) == (p >> 10)) atomicAdd(&lh[copy * HSTRIDE + (key & 1023u)], 1u);
        }
    }
    __syncthreads();

    unsigned* gh = hist + ((size_t)job * CHUNKS + chunk) * 2048;
    for (int i = tid; i < 2048; i += 256)
        gh[i] = lh[i] + lh[HSTRIDE + i] + lh[2 * HSTRIDE + i] + lh[3 * HSTRIDE + i];
    if (PASS == 1 && localnan) atomicAdd(&nanCnt[job], localnan);
}

// ---------------- per-pass scan: find bin containing target rank ----------------
template<int PASS>
__global__ void scan_pass(const unsigned* __restrict__ hist, unsigned* __restrict__ pref,
                          unsigned* __restrict__ krem, const unsigned* __restrict__ nanCnt,
                          float* __restrict__ med)
{
    constexpr int NBINS = (PASS == 3) ? 1024 : 2048;
    constexpr int PER   = NBINS / 256;
    __shared__ unsigned psum[256];
    __shared__ unsigned selseg;
    __shared__ unsigned selbase;
    const int tid = threadIdx.x;
    const int job = blockIdx.x;
    const unsigned* h = hist + (size_t)job * CHUNKS * 2048;

    unsigned bins[PER];
    unsigned s = 0;
    #pragma unroll
    for (int i = 0; i < PER; ++i) {
        unsigned v = 0;
        int bin = tid * PER + i;
        #pragma unroll
        for (int c = 0; c < CHUNKS; ++c) v += h[(size_t)c * 2048 + bin];
        bins[i] = v; s += v;
    }
    psum[tid] = s;
    __syncthreads();

    unsigned target = (PASS == 1) ? (unsigned)KMED : krem[job];
    if (tid == 0) {
        unsigned cum = 0; unsigned seg = 255, base = 0;
        for (int t2 = 0; t2 < 256; ++t2) {
            if (cum + psum[t2] > target) { seg = t2; base = cum; break; }
            cum += psum[t2];
        }
        selseg = seg; selbase = base;
    }
    __syncthreads();

    if (tid == (int)selseg) {
        unsigned cum = selbase;
        #pragma unroll
        for (int i = 0; i < PER; ++i) {
            if (cum + bins[i] > target) {
                unsigned bin = (unsigned)(tid * PER + i);
                if (PASS == 1) { pref[job] = bin << 21; krem[job] = target - cum; }
                else if (PASS == 2) { pref[job] |= bin << 10; krem[job] = target - cum; }
                else {
                    unsigned key = pref[job] | bin;
                    unsigned u = (key & 0x80000000u) ? (key ^ 0x80000000u) : ~key;
                    float v = __uint_as_float(u);
                    med[job] = (nanCnt[job] > 0u) ? -INFINITY : v;
                }
                break;
            }
            cum += bins[i];
        }
    }
}

// ---------------- argmax over windows (first-wins) ----------------
__global__ void argmax_kernel(const float* __restrict__ med, int* __restrict__ best)
{
    int b = threadIdx.x;
    if (b < NB) {
        float mx = -INFINITY; int bi = 0;
        for (int w = 0; w < W; ++w) {
            float v = med[b * W + w];
            if (v > mx) { mx = v; bi = w; }
        }
        best[b] = bi;
    }
}

// ---------------- emit selected window (real plane, imag plane) ----------------
__global__ void gather_kernel(const float2* __restrict__ auxS, const int* __restrict__ best,
                              float* __restrict__ out)
{
    int i = blockIdx.x * blockDim.x + threadIdx.x;
    if (i >= NB * NVAL) return;
    int b = i / NVAL;
    int r = i - b * NVAL;
    float2 v = auxS[((size_t)b * TROWS + (size_t)best[b] * HS) * NBIN + r];
    out[((size_t)(b * 2) + 0) * NVAL + r] = v.x;
    out[((size_t)(b * 2) + 1) * NVAL + r] = v.y;
}

// ---------------- launch ----------------
extern "C" void kernel_launch(void* const* d_in, const int* in_sizes, int n_in,
                              void* d_out, int out_size, void* d_ws, size_t ws_size,
                              hipStream_t stream)
{
    const float* mix = (const float*)d_in[0];
    const float* aux = (const float*)d_in[1];
    float* out = (float*)d_out;
    char* ws = (char*)d_ws;

    float2*   mixS = (float2*)(ws + MIXS_OFF);
    float2*   auxS = (float2*)(ws + AUXS_OFF);
    unsigned* hist = (unsigned*)(ws + HIST_OFF);
    float2*   twg  = (float2*)(ws + TW_OFF);
    unsigned* nanC = (unsigned*)(ws + NAN_OFF);
    unsigned* pref = (unsigned*)(ws + PREF_OFF);
    unsigned* krem = (unsigned*)(ws + KREM_OFF);
    float*    med  = (float*)(ws + MED_OFF);
    int*      best = (int*)(ws + BEST_OFF);

    // only NaN counters need zeroing (hist is fully overwritten before each scan)
    hipMemsetAsync(nanC, 0, NAN_BYTES, stream);
    build_table<<<1, 256, 0, stream>>>(twg);

    constexpr int FPB = 4;
    stft_fft<FPB><<<dim3((TM + FPB - 1) / FPB, NB), 256, 0, stream>>>(mix, twg, LMIX, TM, TM, mixS);
    stft_fft<FPB><<<dim3((TROWS + FPB - 1) / FPB, NB), 256, 0, stream>>>(aux, twg, LAUX, TA, TROWS, auxS);

    sim_pass<1><<<dim3(CHUNKS, NJOBS), 256, 0, stream>>>(mixS, auxS, hist, nanC, pref);
    scan_pass<1><<<NJOBS, 256, 0, stream>>>(hist, pref, krem, nanC, med);
    sim_pass<2><<<dim3(CHUNKS, NJOBS), 256, 0, stream>>>(mixS, auxS, hist, nanC, pref);
    scan_pass<2><<<NJOBS, 256, 0, stream>>>(hist, pref, krem, nanC, med);
    sim_pass<3><<<dim3(CHUNKS, NJOBS), 256, 0, stream>>>(mixS, auxS, hist, nanC, pref);
    scan_pass<3><<<NJOBS, 256, 0, stream>>>(hist, pref, krem, nanC, med);

    argmax_kernel<<<1, 64, 0, stream>>>(med, best);
    gather_kernel<<<(NB * NVAL + 255) / 256, 256, 0, stream>>>(auxS, best, out);
}

// Round 3
// 196.060 us; speedup vs baseline: 2.4827x; 1.5486x over previous
//
#include <hip/hip_runtime.h>
#include <math.h>

// ---------------- problem constants ----------------
constexpr int NFFT  = 256;
constexpr int HOP   = 64;
constexpr int NBIN  = 129;          // rfft bins
constexpr int NB    = 8;            // batch
constexpr int LMIX  = 65536;
constexpr int LAUX  = 262144;
constexpr int TM    = 1025;         // mix frames
constexpr int TA    = 4097;         // aux frames
constexpr int TROWS = 4175;         // aux frames + zero pad (78)
constexpr int HS    = 126;
constexpr int W     = 26;           // windows
constexpr int NJOBS = NB * W;       // 208
constexpr int NVAL  = TM * NBIN;    // 132225 values per (b,w)
constexpr int KMED  = (NVAL - 1) / 2; // 66112
constexpr int CHUNKS = 8;           // blocks per job in sim passes

// ---------------- workspace layout (bytes) ----------------
constexpr size_t MIXN_OFF  = 0;
constexpr size_t MIXN_BYTES = (size_t)NB * TM * NBIN * sizeof(float2);      // 8,462,400
constexpr size_t AUXN_OFF  = MIXN_OFF + MIXN_BYTES;
constexpr size_t AUXN_BYTES = (size_t)NB * TROWS * NBIN * sizeof(float2);   // 34,468,800
constexpr size_t HIST_OFF  = AUXN_OFF + AUXN_BYTES;
constexpr size_t HIST_BYTES = (size_t)NJOBS * CHUNKS * 2048 * 4;            // 13,631,488
constexpr size_t TW_OFF    = HIST_OFF + HIST_BYTES;
constexpr size_t TW_BYTES  = 256 * sizeof(float2);
constexpr size_t NAN_OFF   = TW_OFF + TW_BYTES;
constexpr size_t NAN_BYTES = (size_t)NJOBS * 4;                              // 832
constexpr size_t PREF_OFF  = NAN_OFF + 832;
constexpr size_t KREM_OFF  = PREF_OFF + 832;
constexpr size_t MED_OFF   = KREM_OFF + 832;
constexpr size_t BEST_OFF  = MED_OFF + 832;

// ---------------- twiddle table: tw[j] = e^{-2*pi*i*j/256}, built in double ----------------
__global__ void build_table(float2* __restrict__ tw)
{
    int i = threadIdx.x;
    double ang = (double)i * (-2.0 * 3.14159265358979323846 / 256.0);
    tw[i] = make_float2((float)cos(ang), (float)sin(ang));
}

// ---------------- STFT via Cooley-Tukey 256 = 16 x 16 ----------------
// X[k] = sum_{n1=0..15} dk^{n1} * Y[n1][k mod 16],  dk = e^{-2pi i k/256}
// Y[n1][r] = sum_{n2=0..15} x[n1 + 16 n2] * e^{-2pi i r n2 / 16}
// NORM: write X/|X| (NaN where |X|=0 or padded row) — feeds the sim passes.
template<int FPB, bool NORM>
__global__ void stft_fft(const float* __restrict__ x, const float2* __restrict__ twg,
                         int L, int Tframes, int Trows, float2* __restrict__ out)
{
    constexpr int NX = 64 * (FPB - 1) + NFFT;   // shared sample span (448 for FPB=4)
    __shared__ float  xs[NX];
    __shared__ float2 Y[FPB][16][16];
    __shared__ float2 cis16[16];

    const int tid = threadIdx.x;
    const int b   = blockIdx.y;
    const int f0  = blockIdx.x * FPB;

    if (tid < 16) cis16[tid] = twg[(16 * tid) & 255];

    // load the union of this block's frames once (reflect padding)
    for (int i = tid; i < NX; i += 256) {
        int j = f0 * HOP + i - 128;
        if (j < 0) j = -j;
        if (j >= L) j = 2 * L - 2 - j;
        xs[i] = x[(size_t)b * L + j];
    }
    __syncthreads();

    // stage B: inner 16-point DFTs. thread owns fixed (n1, r), loops frames.
    const int n1 = (tid >> 4) & 15;
    const int r  = tid & 15;
    #pragma unroll
    for (int f = 0; f < FPB; ++f) {
        float re = 0.f, im = 0.f;
        int idx = 0;
        #pragma unroll
        for (int n2 = 0; n2 < 16; ++n2) {
            float  v = xs[f * HOP + n1 + 16 * n2];
            float2 t = cis16[idx];
            re = fmaf(v, t.x, re);
            im = fmaf(v, t.y, im);
            idx = (idx + r) & 15;
        }
        Y[f][n1][r] = make_float2(re, im);
    }
    __syncthreads();

    // stage C: combine with per-thread twiddle recurrence
    const float QNAN = __int_as_float(0x7FC00000);
    for (int jj = tid; jj < FPB * NBIN; jj += 256) {
        int f  = jj / NBIN;
        int k  = jj - f * NBIN;
        int fr = f0 + f;
        if (fr >= Trows) continue;
        float2 o;
        if (fr < Tframes) {
            float2 dk = twg[k];
            float tr = 1.f, ti = 0.f;
            float ar = 0.f, ai = 0.f;
            #pragma unroll
            for (int s = 0; s < 16; ++s) {
                float2 y = Y[f][s][k & 15];
                ar = fmaf(tr, y.x, ar); ar = fmaf(-ti, y.y, ar);
                ai = fmaf(tr, y.y, ai); ai = fmaf( ti, y.x, ai);
                float nr = tr * dk.x - ti * dk.y;
                ti = fmaf(tr, dk.y, ti * dk.x);
                tr = nr;
            }
            if (NORM) {
                float inv = rsqrtf(ar * ar + ai * ai);   // |X|=0 -> inf -> NaN, as desired
                o = make_float2(ar * inv, ai * inv);
            } else {
                o = make_float2(ar, ai);
            }
        } else {
            o = NORM ? make_float2(QNAN, QNAN) : make_float2(0.f, 0.f);
        }
        out[((size_t)b * Trows + fr) * NBIN + k] = o;
    }
}

// ---------------- sortable key flip ----------------
__device__ __forceinline__ unsigned flip_key(float s) {
    unsigned u = __float_as_uint(s);
    return (u & 0x80000000u) ? ~u : (u | 0x80000000u);
}

// PASS 1: bin = key>>21 (11 bits), count NaNs
// PASS 2: among keys with top-11 == pref, bin = (key>>10)&2047
// PASS 3: among keys with top-22 == pref, bin = key & 1023
template<int PASS>
__device__ __forceinline__ void hist_one(float s, unsigned p, unsigned* lhc, unsigned& localnan)
{
    unsigned key = flip_key(s);
    if (PASS == 1) {
        if (!(s == s)) localnan++;
        atomicAdd(&lhc[key >> 21], 1u);
    } else if (PASS == 2) {
        if ((key >> 21) == (p >> 21)) atomicAdd(&lhc[(key >> 10) & 2047u], 1u);
    } else {
        if ((key >> 10) == (p >> 10)) atomicAdd(&lhc[key & 1023u], 1u);
    }
}

// ---------------- similarity + histogram passes ----------------
// mixN/auxN are pre-normalized: s = mx*ax + my*ay  (1 mul + 1 fma per element)
template<int PASS>
__global__ void sim_pass(const float2* __restrict__ mixN, const float2* __restrict__ auxN,
                         unsigned* __restrict__ hist, unsigned* __restrict__ nanCnt,
                         const unsigned* __restrict__ pref)
{
    constexpr int NCOPY   = 2;
    constexpr int HSTRIDE = 2049;                 // bank-offset copies
    __shared__ unsigned lh[NCOPY * HSTRIDE];      // 16,392 B -> 8 blocks/CU
    const int tid   = threadIdx.x;
    const int chunk = blockIdx.x;   // 0..CHUNKS-1
    const int job   = blockIdx.y;   // 0..207
    const int b = job / W;
    const int w = job - b * W;
    unsigned* lhc = lh + ((tid >> 4) & (NCOPY - 1)) * HSTRIDE;

    for (int i = tid; i < NCOPY * HSTRIDE; i += 256) lh[i] = 0;
    unsigned p = (PASS == 1) ? 0u : pref[job];
    __syncthreads();

    unsigned localnan = 0;
    const float2* mrow = mixN + (size_t)b * TM * NBIN;
    const float2* arow = auxN + ((size_t)b * TROWS + (size_t)w * HS) * NBIN;

    // both mrow and arow start at element parity (b&1); align float4 accesses
    const int pad = b & 1;
    const int lim = pad + ((NVAL - pad) & ~1);    // exclusive end of vectorized region

    for (int i = pad + (chunk * 256 + tid) * 2; i < lim; i += CHUNKS * 512) {
        float4 mv = *reinterpret_cast<const float4*>(mrow + i);
        float4 av = *reinterpret_cast<const float4*>(arow + i);
        float s0 = fmaf(mv.x, av.x, mv.y * av.y);
        float s1 = fmaf(mv.z, av.z, mv.w * av.w);
        hist_one<PASS>(s0, p, lhc, localnan);
        hist_one<PASS>(s1, p, lhc, localnan);
    }
    if (chunk == 0 && tid == 0) {                 // the one leftover scalar element
        int ie = pad ? 0 : NVAL - 1;
        float2 m = mrow[ie];
        float2 a = arow[ie];
        hist_one<PASS>(fmaf(m.x, a.x, m.y * a.y), p, lhc, localnan);
    }
    __syncthreads();

    unsigned* gh = hist + ((size_t)job * CHUNKS + chunk) * 2048;
    for (int i = tid; i < 2048; i += 256) gh[i] = lh[i] + lh[HSTRIDE + i];
    if (PASS == 1 && localnan) atomicAdd(&nanCnt[job], localnan);
}

// ---------------- per-pass scan: find bin containing target rank ----------------
template<int PASS>
__global__ void scan_pass(const unsigned* __restrict__ hist, unsigned* __restrict__ pref,
                          unsigned* __restrict__ krem, const unsigned* __restrict__ nanCnt,
                          float* __restrict__ med)
{
    constexpr int NBINS = (PASS == 3) ? 1024 : 2048;
    constexpr int PER   = NBINS / 256;
    __shared__ unsigned psum[256];
    __shared__ unsigned selseg;
    __shared__ unsigned selbase;
    const int tid = threadIdx.x;
    const int job = blockIdx.x;
    const unsigned* h = hist + (size_t)job * CHUNKS * 2048;

    unsigned bins[PER];
    unsigned s = 0;
    #pragma unroll
    for (int i = 0; i < PER; ++i) {
        unsigned v = 0;
        int bin = tid * PER + i;
        #pragma unroll
        for (int c = 0; c < CHUNKS; ++c) v += h[(size_t)c * 2048 + bin];
        bins[i] = v; s += v;
    }
    psum[tid] = s;
    __syncthreads();

    unsigned target = (PASS == 1) ? (unsigned)KMED : krem[job];
    if (tid == 0) {
        unsigned cum = 0; unsigned seg = 255, base = 0;
        for (int t2 = 0; t2 < 256; ++t2) {
            if (cum + psum[t2] > target) { seg = t2; base = cum; break; }
            cum += psum[t2];
        }
        selseg = seg; selbase = base;
    }
    __syncthreads();

    if (tid == (int)selseg) {
        unsigned cum = selbase;
        #pragma unroll
        for (int i = 0; i < PER; ++i) {
            if (cum + bins[i] > target) {
                unsigned bin = (unsigned)(tid * PER + i);
                if (PASS == 1) { pref[job] = bin << 21; krem[job] = target - cum; }
                else if (PASS == 2) { pref[job] |= bin << 10; krem[job] = target - cum; }
                else {
                    unsigned key = pref[job] | bin;
                    unsigned u = (key & 0x80000000u) ? (key ^ 0x80000000u) : ~key;
                    float v = __uint_as_float(u);
                    med[job] = (nanCnt[job] > 0u) ? -INFINITY : v;
                }
                break;
            }
            cum += bins[i];
        }
    }
}

// ---------------- argmax over windows (first-wins) ----------------
__global__ void argmax_kernel(const float* __restrict__ med, int* __restrict__ best)
{
    int b = threadIdx.x;
    if (b < NB) {
        float mx = -INFINITY; int bi = 0;
        for (int w = 0; w < W; ++w) {
            float v = med[b * W + w];
            if (v > mx) { mx = v; bi = w; }
        }
        best[b] = bi;
    }
}

// ---------------- recompute raw STFT for the selected window, write output ----------------
template<int FPB>
__global__ void gather_stft(const float* __restrict__ x, const float2* __restrict__ twg,
                            const int* __restrict__ best, float* __restrict__ out)
{
    constexpr int NX = 64 * (FPB - 1) + NFFT;
    __shared__ float  xs[NX];
    __shared__ float2 Y[FPB][16][16];
    __shared__ float2 cis16[16];

    const int tid = threadIdx.x;
    const int b   = blockIdx.y;
    const int t0  = blockIdx.x * FPB;           // output row base (0..1024)
    const int fr0 = best[b] * HS + t0;          // aux frame base

    if (tid < 16) cis16[tid] = twg[(16 * tid) & 255];

    for (int i = tid; i < NX; i += 256) {
        int j = fr0 * HOP + i - 128;
        if (j < 0) j = -j;
        if (j >= LAUX) j = 2 * LAUX - 2 - j;
        j = max(0, min(LAUX - 1, j));           // safety clamp
        xs[i] = x[(size_t)b * LAUX + j];
    }
    __syncthreads();

    const int n1 = (tid >> 4) & 15;
    const int r  = tid & 15;
    #pragma unroll
    for (int f = 0; f < FPB; ++f) {
        float re = 0.f, im = 0.f;
        int idx = 0;
        #pragma unroll
        for (int n2 = 0; n2 < 16; ++n2) {
            float  v = xs[f * HOP + n1 + 16 * n2];
            float2 t = cis16[idx];
            re = fmaf(v, t.x, re);
            im = fmaf(v, t.y, im);
            idx = (idx + r) & 15;
        }
        Y[f][n1][r] = make_float2(re, im);
    }
    __syncthreads();

    for (int jj = tid; jj < FPB * NBIN; jj += 256) {
        int f  = jj / NBIN;
        int k  = jj - f * NBIN;
        int t  = t0 + f;
        if (t >= TM) continue;
        float ar = 0.f, ai = 0.f;
        if (fr0 + f < TA) {                     // padded rows are zero
            float2 dk = twg[k];
            float tr = 1.f, ti = 0.f;
            #pragma unroll
            for (int s = 0; s < 16; ++s) {
                float2 y = Y[f][s][k & 15];
                ar = fmaf(tr, y.x, ar); ar = fmaf(-ti, y.y, ar);
                ai = fmaf(tr, y.y, ai); ai = fmaf( ti, y.x, ai);
                float nr = tr * dk.x - ti * dk.y;
                ti = fmaf(tr, dk.y, ti * dk.x);
                tr = nr;
            }
        }
        size_t o = (size_t)t * NBIN + k;
        out[(size_t)(b * 2 + 0) * NVAL + o] = ar;
        out[(size_t)(b * 2 + 1) * NVAL + o] = ai;
    }
}

// ---------------- launch ----------------
extern "C" void kernel_launch(void* const* d_in, const int* in_sizes, int n_in,
                              void* d_out, int out_size, void* d_ws, size_t ws_size,
                              hipStream_t stream)
{
    const float* mix = (const float*)d_in[0];
    const float* aux = (const float*)d_in[1];
    float* out = (float*)d_out;
    char* ws = (char*)d_ws;

    float2*   mixN = (float2*)(ws + MIXN_OFF);
    float2*   auxN = (float2*)(ws + AUXN_OFF);
    unsigned* hist = (unsigned*)(ws + HIST_OFF);
    float2*   twg  = (float2*)(ws + TW_OFF);
    unsigned* nanC = (unsigned*)(ws + NAN_OFF);
    unsigned* pref = (unsigned*)(ws + PREF_OFF);
    unsigned* krem = (unsigned*)(ws + KREM_OFF);
    float*    med  = (float*)(ws + MED_OFF);
    int*      best = (int*)(ws + BEST_OFF);

    hipMemsetAsync(nanC, 0, NAN_BYTES, stream);
    build_table<<<1, 256, 0, stream>>>(twg);

    constexpr int FPB = 4;
    stft_fft<FPB, true><<<dim3((TM + FPB - 1) / FPB, NB), 256, 0, stream>>>(mix, twg, LMIX, TM, TM, mixN);
    stft_fft<FPB, true><<<dim3((TROWS + FPB - 1) / FPB, NB), 256, 0, stream>>>(aux, twg, LAUX, TA, TROWS, auxN);

    sim_pass<1><<<dim3(CHUNKS, NJOBS), 256, 0, stream>>>(mixN, auxN, hist, nanC, pref);
    scan_pass<1><<<NJOBS, 256, 0, stream>>>(hist, pref, krem, nanC, med);
    sim_pass<2><<<dim3(CHUNKS, NJOBS), 256, 0, stream>>>(mixN, auxN, hist, nanC, pref);
    scan_pass<2><<<NJOBS, 256, 0, stream>>>(hist, pref, krem, nanC, med);
    sim_pass<3><<<dim3(CHUNKS, NJOBS), 256, 0, stream>>>(mixN, auxN, hist, nanC, pref);
    scan_pass<3><<<NJOBS, 256, 0, stream>>>(hist, pref, krem, nanC, med);

    argmax_kernel<<<1, 64, 0, stream>>>(med, best);
    gather_stft<FPB><<<dim3((TM + FPB - 1) / FPB, NB), 256, 0, stream>>>(aux, twg, best, out);
}